// Round 1
// baseline (438.620 us; speedup 1.0000x reference)
//
#include <hip/hip_runtime.h>
#include <stdint.h>

#define DEV static __device__ __forceinline__

typedef _Float16 half8 __attribute__((ext_vector_type(8)));
typedef float f32x4 __attribute__((ext_vector_type(4)));

// Problem constants (B=2, S=2048, D=2048, H=16, HD=128)
constexpr int Bc = 2, Sc = 2048, Dc = 2048, Hc = 16, HDc = 128;
constexpr int D3c = 3 * Dc;   // 6144
constexpr int Mc = Bc * Sc;   // 4096

// -------- helpers --------
DEV void gl_lds16(const void* g, void* l) {
    // async 16B/lane global->LDS; LDS dest = wave-uniform base + lane*16
    __builtin_amdgcn_global_load_lds(
        (const __attribute__((address_space(1))) unsigned int*)g,
        (__attribute__((address_space(3))) unsigned int*)l,
        16, 0, 0);
}

// ======================= cast fp32 -> fp16 =======================
__global__ __launch_bounds__(256) void cast_f16_kernel(
    const float* __restrict__ in, _Float16* __restrict__ out)
{
    int i = blockIdx.x * 256 + threadIdx.x;          // 8 elems per thread
    const float4* p = (const float4*)in;
    float4 a = p[i * 2], b = p[i * 2 + 1];
    half8 hv;
    hv[0] = (_Float16)a.x; hv[1] = (_Float16)a.y; hv[2] = (_Float16)a.z; hv[3] = (_Float16)a.w;
    hv[4] = (_Float16)b.x; hv[5] = (_Float16)b.y; hv[6] = (_Float16)b.z; hv[7] = (_Float16)b.w;
    *(half8*)(out + (size_t)i * 8) = hv;
}

// ============== transpose + cast: in[R][C] f32 -> out[C][R] f16 ==============
__global__ __launch_bounds__(256) void transpose_cast_kernel(
    const float* __restrict__ in, _Float16* __restrict__ out, int R, int C)
{
    __shared__ float ls[64][65];
    const int t = threadIdx.x;
    const int r0 = blockIdx.y * 64, c0 = blockIdx.x * 64;
    const int rr = t >> 6, cc = t & 63;
#pragma unroll
    for (int i = 0; i < 16; ++i) {
        int r = i * 4 + rr;
        ls[r][cc] = in[(size_t)(r0 + r) * C + c0 + cc];
    }
    __syncthreads();
#pragma unroll
    for (int i = 0; i < 16; ++i) {
        int r = i * 4 + rr;   // output-row offset within the c-tile
        out[(size_t)(c0 + r) * R + r0 + cc] = (_Float16)ls[cc][r];
    }
}

// ====== V transpose: qkv[b,s, h*384+256+d] -> vt[(bh*128+d)*2048 + s] ======
__global__ __launch_bounds__(256) void transpose_v_kernel(
    const uint16_t* __restrict__ qkv, uint16_t* __restrict__ vt)
{
    __shared__ uint32_t ls[64][65];
    const int t = threadIdx.x;
    const int s0 = blockIdx.x * 64, d0 = blockIdx.y * 64, bh = blockIdx.z;
    const int b = bh >> 4, h = bh & 15;
    const int rr = t >> 6, cc = t & 63;
#pragma unroll
    for (int i = 0; i < 16; ++i) {
        int r = i * 4 + rr;   // s index
        ls[r][cc] = qkv[(size_t)(b * Sc + s0 + r) * D3c + h * 384 + 256 + d0 + cc];
    }
    __syncthreads();
#pragma unroll
    for (int i = 0; i < 16; ++i) {
        int r = i * 4 + rr;   // d index
        vt[(size_t)(bh * HDc + d0 + r) * Sc + s0 + cc] = (uint16_t)ls[cc][r];
    }
}

// ======================= GEMM: C[M,N] = A[M,K] @ Bt[N,K]^T + bias =======================
// 128x128 tile, BK=64, 256 threads (2x2 waves of 64x64), f16 MFMA 16x16x32,
// global_load_lds staging with XOR-swizzled source pointers.
template <int BF16OUT>
__global__ __launch_bounds__(256, 2) void gemm_bt_kernel(
    const _Float16* __restrict__ A, const _Float16* __restrict__ Bt,
    const float* __restrict__ bias, void* __restrict__ Cout,
    int M, int N, int K)
{
    __shared__ __align__(16) char smem[32768];
    char* sA = smem;            // [128 rows][8 chunks16B] swizzled: chunk ^= row&7
    char* sB = smem + 16384;
    const int t = threadIdx.x, w = t >> 6, lane = t & 63;
    const int quad = lane >> 4, l15 = lane & 15;
    const int wr = w >> 1, wc = w & 1;
    const int n0 = blockIdx.x * 128, m0 = blockIdx.y * 128;

    const f32x4 vzero = {0.f, 0.f, 0.f, 0.f};
    f32x4 acc[4][4];
#pragma unroll
    for (int i = 0; i < 4; ++i)
#pragma unroll
        for (int j = 0; j < 4; ++j) acc[i][j] = vzero;

    const int kiters = K >> 6;
    for (int kk = 0; kk < kiters; ++kk) {
#pragma unroll
        for (int i = 0; i < 4; ++i) {
            int c = i * 256 + t;
            int row = c >> 3, kbs = c & 7, kact = kbs ^ (row & 7);
            gl_lds16(A + (size_t)(m0 + row) * K + kk * 64 + kact * 8,
                     sA + (i * 256 + w * 64) * 16);
        }
#pragma unroll
        for (int i = 0; i < 4; ++i) {
            int c = i * 256 + t;
            int row = c >> 3, kbs = c & 7, kact = kbs ^ (row & 7);
            gl_lds16(Bt + (size_t)(n0 + row) * K + kk * 64 + kact * 8,
                     sB + (i * 256 + w * 64) * 16);
        }
        __syncthreads();
#pragma unroll
        for (int ks = 0; ks < 2; ++ks) {
            half8 af[4], bf[4];
#pragma unroll
            for (int mt = 0; mt < 4; ++mt) {
                int row = wr * 64 + mt * 16 + l15;
                int kact = (ks * 4 + quad) ^ (l15 & 7);
                af[mt] = *(const half8*)(sA + row * 128 + kact * 16);
            }
#pragma unroll
            for (int nt = 0; nt < 4; ++nt) {
                int row = wc * 64 + nt * 16 + l15;
                int kact = (ks * 4 + quad) ^ (l15 & 7);
                bf[nt] = *(const half8*)(sB + row * 128 + kact * 16);
            }
#pragma unroll
            for (int mt = 0; mt < 4; ++mt)
#pragma unroll
                for (int nt = 0; nt < 4; ++nt)
                    acc[mt][nt] = __builtin_amdgcn_mfma_f32_16x16x32_f16(
                        af[mt], bf[nt], acc[mt][nt], 0, 0, 0);
        }
        __syncthreads();
    }

    // epilogue: C/D layout col=lane&15, row=quad*4+reg (m89-verified)
#pragma unroll
    for (int nt = 0; nt < 4; ++nt) {
        int col = n0 + wc * 64 + nt * 16 + l15;
        float bv = bias[col];
#pragma unroll
        for (int mt = 0; mt < 4; ++mt)
#pragma unroll
            for (int r = 0; r < 4; ++r) {
                int row = m0 + wr * 64 + mt * 16 + quad * 4 + r;
                float v = acc[mt][nt][r] + bv;
                if (BF16OUT) ((_Float16*)Cout)[(size_t)row * N + col] = (_Float16)v;
                else         ((float*)Cout)[(size_t)row * N + col] = v;
            }
    }
}

// ======================= flash attention =======================
// grid (16 qtiles, 32 bh); block 256 = 4 waves; BM=128 (wave: 32 q rows), BN=64 kv.
// Online softmax in registers; P routed through LDS for the A-operand layout.
__global__ __launch_bounds__(256, 2) void flash_kernel(
    const _Float16* __restrict__ qkv, const _Float16* __restrict__ vt,
    _Float16* __restrict__ attn)
{
    __shared__ __align__(16) char smem[49152];
    char* sK = smem;            // [64 kv][16 chunks] swizzled ^(row&15)
    char* sV = smem + 16384;    // [128 d][8 chunks]  swizzled ^(row&7)
    char* sP = smem + 32768;    // [128 q][8 chunks]  swizzled ^(row&7)

    const int t = threadIdx.x, w = t >> 6, lane = t & 63;
    const int quad = lane >> 4, l15 = lane & 15;
    const int qt = 15 - blockIdx.x;          // heavy tiles first
    const int bh = blockIdx.y;
    const int b = bh >> 4, h = bh & 15;
    const int q0 = qt * 128;

    // Q fragments straight from global (once per block)
    half8 qf[2][4];
#pragma unroll
    for (int mt = 0; mt < 2; ++mt)
#pragma unroll
        for (int ks = 0; ks < 4; ++ks) {
            const _Float16* p = qkv +
                (size_t)(b * Sc + q0 + w * 32 + mt * 16 + l15) * D3c +
                h * 384 + ks * 32 + quad * 8;
            qf[mt][ks] = *(const half8*)p;
        }

    const f32x4 vzero = {0.f, 0.f, 0.f, 0.f};
    f32x4 o[2][8];
#pragma unroll
    for (int mt = 0; mt < 2; ++mt)
#pragma unroll
        for (int dt = 0; dt < 8; ++dt) o[mt][dt] = vzero;
    float m_st[2][4], l_st[2][4];
#pragma unroll
    for (int mt = 0; mt < 2; ++mt)
#pragma unroll
        for (int r = 0; r < 4; ++r) { m_st[mt][r] = -1e30f; l_st[mt][r] = 0.f; }

    const float kScale = 0.08838834764831845f * 1.4426950408889634f; // 1/sqrt(128)*log2(e)
    const int nkt = 2 * qt + 2;

    for (int kt = 0; kt < nkt; ++kt) {
        // ---- stage K tile [64 kv][128 d] ----
#pragma unroll
        for (int i = 0; i < 4; ++i) {
            int c = i * 256 + t;
            int row = c >> 4, kbs = c & 15, kact = kbs ^ (row & 15);
            gl_lds16(qkv + (size_t)(b * Sc + kt * 64 + row) * D3c + h * 384 + 128 + kact * 8,
                     sK + (i * 256 + w * 64) * 16);
        }
        // ---- stage Vt tile [128 d][64 kv] ----
#pragma unroll
        for (int i = 0; i < 4; ++i) {
            int c = i * 256 + t;
            int row = c >> 3, kbs = c & 7, kact = kbs ^ (row & 7);
            gl_lds16(vt + (size_t)(bh * HDc + row) * Sc + kt * 64 + kact * 8,
                     sV + (i * 256 + w * 64) * 16);
        }
        __syncthreads();

        // ---- S = Q K^T ----
        f32x4 sf[2][4];
#pragma unroll
        for (int mt = 0; mt < 2; ++mt)
#pragma unroll
            for (int nt = 0; nt < 4; ++nt) sf[mt][nt] = vzero;
#pragma unroll
        for (int ks = 0; ks < 4; ++ks) {
            half8 bk[4];
#pragma unroll
            for (int nt = 0; nt < 4; ++nt) {
                int row = nt * 16 + l15;
                int kact = (ks * 4 + quad) ^ l15;
                bk[nt] = *(const half8*)(sK + row * 256 + kact * 16);
            }
#pragma unroll
            for (int mt = 0; mt < 2; ++mt)
#pragma unroll
                for (int nt = 0; nt < 4; ++nt)
                    sf[mt][nt] = __builtin_amdgcn_mfma_f32_16x16x32_f16(
                        qf[mt][ks], bk[nt], sf[mt][nt], 0, 0, 0);
        }

        // ---- online softmax (registers + shfl) ----
        const bool domask = (kt >= 2 * qt);
        float rm[2][4];
#pragma unroll
        for (int mt = 0; mt < 2; ++mt)
#pragma unroll
            for (int r = 0; r < 4; ++r) rm[mt][r] = -1e30f;
#pragma unroll
        for (int mt = 0; mt < 2; ++mt)
#pragma unroll
            for (int nt = 0; nt < 4; ++nt)
#pragma unroll
                for (int r = 0; r < 4; ++r) {
                    float v = sf[mt][nt][r] * kScale;
                    if (domask) {
                        int col = kt * 64 + nt * 16 + l15;
                        int rowq = q0 + w * 32 + mt * 16 + quad * 4 + r;
                        if (col > rowq) v = -1e30f;
                    }
                    sf[mt][nt][r] = v;
                    rm[mt][r] = fmaxf(rm[mt][r], v);
                }
#pragma unroll
        for (int mt = 0; mt < 2; ++mt)
#pragma unroll
            for (int r = 0; r < 4; ++r) {
                float v = rm[mt][r];
                v = fmaxf(v, __shfl_xor(v, 1, 16));
                v = fmaxf(v, __shfl_xor(v, 2, 16));
                v = fmaxf(v, __shfl_xor(v, 4, 16));
                v = fmaxf(v, __shfl_xor(v, 8, 16));
                rm[mt][r] = v;
            }
        float alpha[2][4], rs[2][4];
#pragma unroll
        for (int mt = 0; mt < 2; ++mt)
#pragma unroll
            for (int r = 0; r < 4; ++r) {
                float mn = fmaxf(m_st[mt][r], rm[mt][r]);
                alpha[mt][r] = __builtin_amdgcn_exp2f(m_st[mt][r] - mn);
                m_st[mt][r] = mn;
                rs[mt][r] = 0.f;
            }
        // P = exp2(s - m): write f16 into sP (swizzled), accumulate row sums
#pragma unroll
        for (int mt = 0; mt < 2; ++mt)
#pragma unroll
            for (int nt = 0; nt < 4; ++nt)
#pragma unroll
                for (int r = 0; r < 4; ++r) {
                    float p = __builtin_amdgcn_exp2f(sf[mt][nt][r] - m_st[mt][r]);
                    rs[mt][r] += p;
                    int row = w * 32 + mt * 16 + quad * 4 + r;
                    int col = nt * 16 + l15;
                    int chunk = (col >> 3) ^ (row & 7);
                    *(_Float16*)(sP + row * 128 + chunk * 16 + (col & 7) * 2) = (_Float16)p;
                }
#pragma unroll
        for (int mt = 0; mt < 2; ++mt)
#pragma unroll
            for (int r = 0; r < 4; ++r) {
                float v = rs[mt][r];
                v += __shfl_xor(v, 1, 16);
                v += __shfl_xor(v, 2, 16);
                v += __shfl_xor(v, 4, 16);
                v += __shfl_xor(v, 8, 16);
                l_st[mt][r] = l_st[mt][r] * alpha[mt][r] + v;
            }
        // rescale O
#pragma unroll
        for (int mt = 0; mt < 2; ++mt)
#pragma unroll
            for (int dt = 0; dt < 8; ++dt)
#pragma unroll
                for (int r = 0; r < 4; ++r) o[mt][dt][r] *= alpha[mt][r];
        __syncthreads();   // P ready

        // ---- O += P V ----
#pragma unroll
        for (int kk = 0; kk < 2; ++kk) {
            int chunk = (kk * 4 + quad) ^ (l15 & 7);
            half8 ap[2], bv[8];
#pragma unroll
            for (int mt = 0; mt < 2; ++mt) {
                int row = w * 32 + mt * 16 + l15;
                ap[mt] = *(const half8*)(sP + row * 128 + chunk * 16);
            }
#pragma unroll
            for (int dt = 0; dt < 8; ++dt) {
                int row = dt * 16 + l15;
                bv[dt] = *(const half8*)(sV + row * 128 + chunk * 16);
            }
#pragma unroll
            for (int mt = 0; mt < 2; ++mt)
#pragma unroll
                for (int dt = 0; dt < 8; ++dt)
                    o[mt][dt] = __builtin_amdgcn_mfma_f32_16x16x32_f16(
                        ap[mt], bv[dt], o[mt][dt], 0, 0, 0);
        }
        __syncthreads();   // PV reads done before restaging
    }

    // ---- epilogue: O /= l, store to attn[b, s, h*128 + d] (f16) ----
#pragma unroll
    for (int mt = 0; mt < 2; ++mt) {
        float linv[4];
#pragma unroll
        for (int r = 0; r < 4; ++r) linv[r] = 1.0f / l_st[mt][r];
#pragma unroll
        for (int dt = 0; dt < 8; ++dt)
#pragma unroll
            for (int r = 0; r < 4; ++r) {
                int row = q0 + w * 32 + mt * 16 + quad * 4 + r;
                int col = h * HDc + dt * 16 + l15;
                attn[(size_t)(b * Sc + row) * Dc + col] = (_Float16)(o[mt][dt][r] * linv[r]);
            }
    }
}

// ======================= launch =======================
extern "C" void kernel_launch(void* const* d_in, const int* in_sizes, int n_in,
                              void* d_out, int out_size, void* d_ws, size_t ws_size,
                              hipStream_t stream)
{
    (void)in_sizes; (void)n_in; (void)out_size; (void)ws_size;
    const float* x    = (const float*)d_in[0];
    const float* Wqkv = (const float*)d_in[1];
    const float* bqkv = (const float*)d_in[2];
    const float* Wo   = (const float*)d_in[3];
    const float* bo   = (const float*)d_in[4];
    float* out = (float*)d_out;

    // workspace layout (f16 elems); attn aliases xb, vtg aliases wt1 (both dead by then)
    _Float16* xb  = (_Float16*)d_ws;                   // 4096*2048
    _Float16* wt1 = xb  + (size_t)Mc * Dc;             // 6144*2048 (Wqkv^T)
    _Float16* wt2 = wt1 + (size_t)D3c * Dc;            // 2048*2048 (Wo^T)
    _Float16* qkv = wt2 + (size_t)Dc * Dc;             // 4096*6144
    _Float16* vtg  = wt1;                              // 32*128*2048 (V^T), reuses wt1
    _Float16* attn = xb;                               // 4096*2048, reuses xb

    cast_f16_kernel<<<Mc * Dc / 2048, 256, 0, stream>>>(x, xb);
    transpose_cast_kernel<<<dim3(D3c / 64, Dc / 64), 256, 0, stream>>>(Wqkv, wt1, Dc, D3c);
    transpose_cast_kernel<<<dim3(Dc / 64, Dc / 64), 256, 0, stream>>>(Wo, wt2, Dc, Dc);
    gemm_bt_kernel<1><<<dim3(D3c / 128, Mc / 128), 256, 0, stream>>>(
        xb, wt1, bqkv, qkv, Mc, D3c, Dc);
    transpose_v_kernel<<<dim3(Sc / 64, 2, Bc * Hc), 256, 0, stream>>>(
        (const uint16_t*)qkv, (uint16_t*)vtg);
    flash_kernel<<<dim3(16, Bc * Hc), 256, 0, stream>>>(qkv, vtg, attn);
    gemm_bt_kernel<0><<<dim3(Dc / 128, Mc / 128), 256, 0, stream>>>(
        attn, wt2, bo, out, Mc, Dc, Dc);
}

// Round 2
// 392.300 us; speedup vs baseline: 1.1181x; 1.1181x over previous
//
#include <hip/hip_runtime.h>
#include <stdint.h>

#define DEV static __device__ __forceinline__

typedef _Float16 half8 __attribute__((ext_vector_type(8)));
typedef _Float16 half4 __attribute__((ext_vector_type(4)));
typedef float f32x4 __attribute__((ext_vector_type(4)));

// Problem constants (B=2, S=2048, D=2048, H=16, HD=128)
constexpr int Bc = 2, Sc = 2048, Dc = 2048, Hc = 16, HDc = 128;
constexpr int D3c = 3 * Dc;   // 6144
constexpr int Mc = Bc * Sc;   // 4096

// -------- helpers --------
DEV void gl_lds16(const void* g, void* l) {
    // async 16B/lane global->LDS; LDS dest = wave-uniform base + lane*16
    __builtin_amdgcn_global_load_lds(
        (const __attribute__((address_space(1))) unsigned int*)g,
        (__attribute__((address_space(3))) unsigned int*)l,
        16, 0, 0);
}

// ======================= cast fp32 -> fp16 =======================
__global__ __launch_bounds__(256) void cast_f16_kernel(
    const float* __restrict__ in, _Float16* __restrict__ out)
{
    int i = blockIdx.x * 256 + threadIdx.x;          // 8 elems per thread
    const float4* p = (const float4*)in;
    float4 a = p[i * 2], b = p[i * 2 + 1];
    half8 hv;
    hv[0] = (_Float16)a.x; hv[1] = (_Float16)a.y; hv[2] = (_Float16)a.z; hv[3] = (_Float16)a.w;
    hv[4] = (_Float16)b.x; hv[5] = (_Float16)b.y; hv[6] = (_Float16)b.z; hv[7] = (_Float16)b.w;
    *(half8*)(out + (size_t)i * 8) = hv;
}

// ============== transpose + cast: in[R][C] f32 -> out[C][R] f16 ==============
__global__ __launch_bounds__(256) void transpose_cast_kernel(
    const float* __restrict__ in, _Float16* __restrict__ out, int R, int C)
{
    __shared__ float ls[64][65];
    const int t = threadIdx.x;
    const int r0 = blockIdx.y * 64, c0 = blockIdx.x * 64;
    const int rr = t >> 6, cc = t & 63;
#pragma unroll
    for (int i = 0; i < 16; ++i) {
        int r = i * 4 + rr;
        ls[r][cc] = in[(size_t)(r0 + r) * C + c0 + cc];
    }
    __syncthreads();
#pragma unroll
    for (int i = 0; i < 16; ++i) {
        int r = i * 4 + rr;   // output-row offset within the c-tile
        out[(size_t)(c0 + r) * R + r0 + cc] = (_Float16)ls[cc][r];
    }
}

// ====== V transpose: qkv[b,s, h*384+256+d] -> vt[(bh*128+d)*2048 + s] ======
__global__ __launch_bounds__(256) void transpose_v_kernel(
    const uint16_t* __restrict__ qkv, uint16_t* __restrict__ vt)
{
    __shared__ uint32_t ls[64][65];
    const int t = threadIdx.x;
    const int s0 = blockIdx.x * 64, d0 = blockIdx.y * 64, bh = blockIdx.z;
    const int b = bh >> 4, h = bh & 15;
    const int rr = t >> 6, cc = t & 63;
#pragma unroll
    for (int i = 0; i < 16; ++i) {
        int r = i * 4 + rr;   // s index
        ls[r][cc] = qkv[(size_t)(b * Sc + s0 + r) * D3c + h * 384 + 256 + d0 + cc];
    }
    __syncthreads();
#pragma unroll
    for (int i = 0; i < 16; ++i) {
        int r = i * 4 + rr;   // d index
        vt[(size_t)(bh * HDc + d0 + r) * Sc + s0 + cc] = (uint16_t)ls[cc][r];
    }
}

// ======================= GEMM: C[M,N] = A[M,K] @ Bt[N,K]^T + bias =======================
// 128x128 tile, BK=64, 256 threads (2x2 waves of 64x64), f16 MFMA 16x16x32,
// global_load_lds staging with XOR-swizzled source pointers.
template <int BF16OUT>
__global__ __launch_bounds__(256, 2) void gemm_bt_kernel(
    const _Float16* __restrict__ A, const _Float16* __restrict__ Bt,
    const float* __restrict__ bias, void* __restrict__ Cout,
    int M, int N, int K)
{
    __shared__ __align__(16) char smem[32768];
    char* sA = smem;            // [128 rows][8 chunks16B] swizzled: chunk ^= row&7
    char* sB = smem + 16384;
    const int t = threadIdx.x, w = t >> 6, lane = t & 63;
    const int quad = lane >> 4, l15 = lane & 15;
    const int wr = w >> 1, wc = w & 1;
    const int n0 = blockIdx.x * 128, m0 = blockIdx.y * 128;

    const f32x4 vzero = {0.f, 0.f, 0.f, 0.f};
    f32x4 acc[4][4];
#pragma unroll
    for (int i = 0; i < 4; ++i)
#pragma unroll
        for (int j = 0; j < 4; ++j) acc[i][j] = vzero;

    const int kiters = K >> 6;
    for (int kk = 0; kk < kiters; ++kk) {
#pragma unroll
        for (int i = 0; i < 4; ++i) {
            int c = i * 256 + t;
            int row = c >> 3, kbs = c & 7, kact = kbs ^ (row & 7);
            gl_lds16(A + (size_t)(m0 + row) * K + kk * 64 + kact * 8,
                     sA + (i * 256 + w * 64) * 16);
        }
#pragma unroll
        for (int i = 0; i < 4; ++i) {
            int c = i * 256 + t;
            int row = c >> 3, kbs = c & 7, kact = kbs ^ (row & 7);
            gl_lds16(Bt + (size_t)(n0 + row) * K + kk * 64 + kact * 8,
                     sB + (i * 256 + w * 64) * 16);
        }
        __syncthreads();
#pragma unroll
        for (int ks = 0; ks < 2; ++ks) {
            half8 af[4], bf[4];
#pragma unroll
            for (int mt = 0; mt < 4; ++mt) {
                int row = wr * 64 + mt * 16 + l15;
                int kact = (ks * 4 + quad) ^ (l15 & 7);
                af[mt] = *(const half8*)(sA + row * 128 + kact * 16);
            }
#pragma unroll
            for (int nt = 0; nt < 4; ++nt) {
                int row = wc * 64 + nt * 16 + l15;
                int kact = (ks * 4 + quad) ^ (l15 & 7);
                bf[nt] = *(const half8*)(sB + row * 128 + kact * 16);
            }
#pragma unroll
            for (int mt = 0; mt < 4; ++mt)
#pragma unroll
                for (int nt = 0; nt < 4; ++nt)
                    acc[mt][nt] = __builtin_amdgcn_mfma_f32_16x16x32_f16(
                        af[mt], bf[nt], acc[mt][nt], 0, 0, 0);
        }
        __syncthreads();
    }

    // epilogue: C/D layout col=lane&15, row=quad*4+reg (m89-verified)
#pragma unroll
    for (int nt = 0; nt < 4; ++nt) {
        int col = n0 + wc * 64 + nt * 16 + l15;
        float bv = bias[col];
#pragma unroll
        for (int mt = 0; mt < 4; ++mt)
#pragma unroll
            for (int r = 0; r < 4; ++r) {
                int row = m0 + wr * 64 + mt * 16 + quad * 4 + r;
                float v = acc[mt][nt][r] + bv;
                if (BF16OUT) ((_Float16*)Cout)[(size_t)row * N + col] = (_Float16)v;
                else         ((float*)Cout)[(size_t)row * N + col] = v;
            }
    }
}

// ======================= flash attention (S^T orientation) =======================
// grid (32 bh, 32 qtiles heavy-first); block 256 = 4 waves; BM=64 q rows (16/wave),
// BN=64 kv per iter. S^T = K·Q^T so the C-layout of S^T IS the B-operand layout of
// mfma_16x16x16 -> P^T feeds PV by in-lane f32->f16 pack, no LDS round-trip.
// O^T accumulated in registers; one LDS transpose at epilogue for coalesced store.
__global__ __launch_bounds__(256, 4) void flash_kernel(
    const _Float16* __restrict__ qkv, const _Float16* __restrict__ vt,
    _Float16* __restrict__ attn)
{
    __shared__ __align__(16) char smem[32768];
    char* sK = smem;            // [64 kv][16 chunks16B] swizzled ^(row&15)
    char* sV = smem + 16384;    // [128 d][8 chunks16B]  swizzled ^(row&7)

    const int t = threadIdx.x, w = t >> 6, lane = t & 63;
    const int quad = lane >> 4, l15 = lane & 15;
    const int bh = blockIdx.x;
    const int qt = 31 - blockIdx.y;          // heavy tiles dispatched first
    const int b = bh >> 4, h = bh & 15;
    const int q0 = qt * 64;
    const int qrow = q0 + w * 16 + l15;      // this lane's q column (S^T orientation)

    // Q fragments straight from global (once per block); B-operand layout == row reads
    half8 qf[4];
#pragma unroll
    for (int ks = 0; ks < 4; ++ks) {
        const _Float16* p = qkv + (size_t)(b * Sc + qrow) * D3c +
                            h * 384 + ks * 32 + quad * 8;
        qf[ks] = *(const half8*)p;
    }

    const f32x4 vzero = {0.f, 0.f, 0.f, 0.f};
    f32x4 o[8];                 // O^T[d = dt*16 + quad*4 + r][q = l15-col]
#pragma unroll
    for (int dt = 0; dt < 8; ++dt) o[dt] = vzero;
    float m_st = -1e30f, l_st = 0.f;   // per-lane stats for q = qrow

    const float kScale = 0.08838834764831845f * 1.4426950408889634f; // 1/sqrt(128)*log2(e)
    const int nkt = qt + 1;

    for (int kt = 0; kt < nkt; ++kt) {
        // ---- stage K tile [64 kv][128 d] ----
#pragma unroll
        for (int i = 0; i < 4; ++i) {
            int c = i * 256 + t;
            int row = c >> 4, kbs = c & 15, kact = kbs ^ (row & 15);
            gl_lds16(qkv + (size_t)(b * Sc + kt * 64 + row) * D3c + h * 384 + 128 + kact * 8,
                     sK + (i * 256 + w * 64) * 16);
        }
        // ---- stage Vt tile [128 d][64 kv] ----
#pragma unroll
        for (int i = 0; i < 4; ++i) {
            int c = i * 256 + t;
            int row = c >> 3, kbs = c & 7, kact = kbs ^ (row & 7);
            gl_lds16(vt + (size_t)(bh * HDc + row) * Sc + kt * 64 + kact * 8,
                     sV + (i * 256 + w * 64) * 16);
        }
        __syncthreads();

        // ---- S^T = K Q^T : D[kv][q], per wave M=64 kv x N=16 q, K=128 d ----
        f32x4 sf[4];
#pragma unroll
        for (int kb = 0; kb < 4; ++kb) sf[kb] = vzero;
#pragma unroll
        for (int ks = 0; ks < 4; ++ks) {
#pragma unroll
            for (int kb = 0; kb < 4; ++kb) {
                int row = kb * 16 + l15;
                int slot = (ks * 4 + quad) ^ l15;
                half8 kf = *(const half8*)(sK + row * 256 + slot * 16);
                sf[kb] = __builtin_amdgcn_mfma_f32_16x16x32_f16(kf, qf[ks], sf[kb], 0, 0, 0);
            }
        }

        // ---- online softmax: lane owns one q column (q=qrow), kv = kb*16+quad*4+r ----
        const bool domask = (kt == qt);
        float rm = -1e30f;
#pragma unroll
        for (int kb = 0; kb < 4; ++kb)
#pragma unroll
            for (int r = 0; r < 4; ++r) {
                float v = sf[kb][r] * kScale;
                if (domask) {
                    int col = kt * 64 + kb * 16 + quad * 4 + r;
                    if (col > qrow) v = -1e30f;
                }
                sf[kb][r] = v;
                rm = fmaxf(rm, v);
            }
        // reduce max across the 4 quads holding this q column
        rm = fmaxf(rm, __shfl_xor(rm, 16, 64));
        rm = fmaxf(rm, __shfl_xor(rm, 32, 64));
        float mn = fmaxf(m_st, rm);
        float alpha = __builtin_amdgcn_exp2f(m_st - mn);
        m_st = mn;

        // P^T pack: exp2(s-m) -> f16; C-layout(kv=quad*4+r) == B-layout(k=quad*4+j)
        half4 pb[4];
        float rs = 0.f;
#pragma unroll
        for (int kb = 0; kb < 4; ++kb)
#pragma unroll
            for (int r = 0; r < 4; ++r) {
                float p = __builtin_amdgcn_exp2f(sf[kb][r] - mn);
                rs += p;
                pb[kb][r] = (_Float16)p;
            }
        rs += __shfl_xor(rs, 16, 64);
        rs += __shfl_xor(rs, 32, 64);
        l_st = l_st * alpha + rs;

        // rescale O^T (alpha is per-lane scalar: all o elements share q=qrow)
#pragma unroll
        for (int dt = 0; dt < 8; ++dt)
#pragma unroll
            for (int r = 0; r < 4; ++r) o[dt][r] *= alpha;

        // ---- O^T += V^T P^T (mfma 16x16x16: A=V^T rows, B=P^T in-register) ----
#pragma unroll
        for (int kb = 0; kb < 4; ++kb) {
#pragma unroll
            for (int dt = 0; dt < 8; ++dt) {
                int row = dt * 16 + l15;
                int slot = (kb * 2 + (quad >> 1)) ^ (l15 & 7);
                half4 vf = *(const half4*)(sV + row * 128 + slot * 16 + (quad & 1) * 8);
                o[dt] = __builtin_amdgcn_mfma_f32_16x16x16f16(vf, pb[kb], o[dt], 0, 0, 0);
            }
        }
        __syncthreads();   // LDS reads done before restaging
    }

    // ---- epilogue: O^T/l -> LDS transpose -> coalesced f16 store ----
    char* sO = smem;      // [64 q][272B rows] (17x16B, conflict-shifted, 16B-aligned)
    float linv = 1.0f / l_st;
#pragma unroll
    for (int dt = 0; dt < 8; ++dt) {
        half4 hv;
#pragma unroll
        for (int r = 0; r < 4; ++r) hv[r] = (_Float16)(o[dt][r] * linv);
        *(half4*)(sO + (w * 16 + l15) * 272 + (dt * 16 + quad * 4) * 2) = hv;
    }
    __syncthreads();
#pragma unroll
    for (int i = 0; i < 4; ++i) {
        int q = i * 16 + (t >> 4);
        int d = (t & 15) * 8;
        half8 hv = *(const half8*)(sO + q * 272 + d * 2);
        *(half8*)(attn + (size_t)(b * Sc + q0 + q) * Dc + h * HDc + d) = hv;
    }
}

// ======================= launch =======================
extern "C" void kernel_launch(void* const* d_in, const int* in_sizes, int n_in,
                              void* d_out, int out_size, void* d_ws, size_t ws_size,
                              hipStream_t stream)
{
    (void)in_sizes; (void)n_in; (void)out_size; (void)ws_size;
    const float* x    = (const float*)d_in[0];
    const float* Wqkv = (const float*)d_in[1];
    const float* bqkv = (const float*)d_in[2];
    const float* Wo   = (const float*)d_in[3];
    const float* bo   = (const float*)d_in[4];
    float* out = (float*)d_out;

    // workspace layout (f16 elems); attn aliases xb, vtg aliases wt1 (both dead by then)
    _Float16* xb  = (_Float16*)d_ws;                   // 4096*2048
    _Float16* wt1 = xb  + (size_t)Mc * Dc;             // 6144*2048 (Wqkv^T)
    _Float16* wt2 = wt1 + (size_t)D3c * Dc;            // 2048*2048 (Wo^T)
    _Float16* qkv = wt2 + (size_t)Dc * Dc;             // 4096*6144
    _Float16* vtg  = wt1;                              // 32*128*2048 (V^T), reuses wt1
    _Float16* attn = xb;                               // 4096*2048, reuses xb

    cast_f16_kernel<<<Mc * Dc / 2048, 256, 0, stream>>>(x, xb);
    transpose_cast_kernel<<<dim3(D3c / 64, Dc / 64), 256, 0, stream>>>(Wqkv, wt1, Dc, D3c);
    transpose_cast_kernel<<<dim3(Dc / 64, Dc / 64), 256, 0, stream>>>(Wo, wt2, Dc, Dc);
    gemm_bt_kernel<1><<<dim3(D3c / 128, Mc / 128), 256, 0, stream>>>(
        xb, wt1, bqkv, qkv, Mc, D3c, Dc);
    transpose_v_kernel<<<dim3(Sc / 64, 2, Bc * Hc), 256, 0, stream>>>(
        (const uint16_t*)qkv, (uint16_t*)vtg);
    flash_kernel<<<dim3(Bc * Hc, 32), 256, 0, stream>>>(qkv, vtg, attn);
    gemm_bt_kernel<0><<<dim3(Dc / 128, Mc / 128), 256, 0, stream>>>(
        attn, wt2, bo, out, Mc, Dc, Dc);
}